// Round 2
// baseline (305.722 us; speedup 1.0000x reference)
//
#include <hip/hip_runtime.h>

// Gather formulation: out(b,c,i,j) = mean of overlapping patch values.
// 7x7 patch grid, origins (128*kh, 128*kw), patch 256x256 -> pixel (i,j) is
// covered by kh in {i>>7 -1, i>>7} ∩ [0,6], kw likewise. Coverage count is
// analytic (1/2/4). Each patch element is read exactly once -> minimal HBM
// traffic (205 MB read + 64 MB write).
//
// R1 change: 4-row tiling per thread. Aligned groups of 4 rows never cross a
// 128-row boundary, so kh-set/pi are shared; 16 independent float4 loads per
// thread (4x MLP), index math amortized 4x, grid 16384 -> 4096 blocks.

__global__ __launch_bounds__(256)
void patch_merge_gather4(const float* __restrict__ patches,  // [B=2,N=49,C=8,256,256]
                         float* __restrict__ out)            // [B,C,1024,1024]
{
    const int tid = blockIdx.x * 256 + threadIdx.x;
    const int j4  = tid & 255;                 // W/4 = 256 float4 columns
    const int i0  = ((tid >> 8) & 255) << 2;   // aligned 4-row group
    const int bc  = tid >> 16;                 // 0..15
    const int b   = bc >> 3;
    const int c   = bc & 7;
    const int j   = j4 << 2;

    const int fh = i0 >> 7;
    const int fw = j  >> 7;

    float4 a0 = {0.f,0.f,0.f,0.f}, a1 = a0, a2 = a0, a3 = a0;
    int cnt = 0;

    #pragma unroll
    for (int dh = -1; dh <= 0; ++dh) {
        const int kh = fh + dh;
        if (kh < 0 || kh > 6) continue;        // block-uniform branch
        const int pi = i0 - (kh << 7);         // row within patch
        #pragma unroll
        for (int dw = -1; dw <= 0; ++dw) {
            const int kw = fw + dw;
            if (kw < 0 || kw > 6) continue;    // uniform per 32-lane span
            const int pj = j - (kw << 7);
            const int n  = kh * 7 + kw;
            const float* p = patches
                + ((size_t)((b * 49 + n) * 8 + c) << 16)   // plane = 256*256
                + (pi << 8) + pj;
            const float4 v0 = *reinterpret_cast<const float4*>(p);
            const float4 v1 = *reinterpret_cast<const float4*>(p + 256);
            const float4 v2 = *reinterpret_cast<const float4*>(p + 512);
            const float4 v3 = *reinterpret_cast<const float4*>(p + 768);
            a0.x += v0.x; a0.y += v0.y; a0.z += v0.z; a0.w += v0.w;
            a1.x += v1.x; a1.y += v1.y; a1.z += v1.z; a1.w += v1.w;
            a2.x += v2.x; a2.y += v2.y; a2.z += v2.z; a2.w += v2.w;
            a3.x += v3.x; a3.y += v3.y; a3.z += v3.z; a3.w += v3.w;
            ++cnt;
        }
    }

    const float inv = 1.0f / ((float)cnt + 1e-8f);  // matches ref's /(wts+eps)
    a0.x *= inv; a0.y *= inv; a0.z *= inv; a0.w *= inv;
    a1.x *= inv; a1.y *= inv; a1.z *= inv; a1.w *= inv;
    a2.x *= inv; a2.y *= inv; a2.z *= inv; a2.w *= inv;
    a3.x *= inv; a3.y *= inv; a3.z *= inv; a3.w *= inv;

    float* o = out + ((size_t)(bc << 10) + i0) * 1024 + j;
    *reinterpret_cast<float4*>(o)        = a0;
    *reinterpret_cast<float4*>(o + 1024) = a1;
    *reinterpret_cast<float4*>(o + 2048) = a2;
    *reinterpret_cast<float4*>(o + 3072) = a3;
}

extern "C" void kernel_launch(void* const* d_in, const int* in_sizes, int n_in,
                              void* d_out, int out_size, void* d_ws, size_t ws_size,
                              hipStream_t stream) {
    const float* patches = (const float*)d_in[0];
    float* out = (float*)d_out;

    // total threads = B*C * (H/4) * (W/4) = 16 * 256 * 256 = 1,048,576
    const int block = 256;
    const int grid  = (16 * 256 * 256) / block;   // 4096

    patch_merge_gather4<<<grid, block, 0, stream>>>(patches, out);
}